// Round 11
// baseline (161.501 us; speedup 1.0000x reference)
//
#include <hip/hip_runtime.h>

#define N_NODES 20000
#define N_EDGES 640000
#define D 128
#define CAP 128      // bucket capacity per node
#define NREG 8       // dst regions (one per XCD under round-robin dispatch)
#define REGSZ 2500   // nodes per region

typedef __attribute__((ext_vector_type(8))) short bf16x8;
typedef __attribute__((ext_vector_type(4))) float f32x4;

__device__ __forceinline__ short f2bf(float f) {
    union { float f; unsigned u; } un; un.f = f;
    unsigned r = un.u + 0x7fff + ((un.u >> 16) & 1);
    return (short)(r >> 16);
}
__device__ __forceinline__ float bflo(unsigned u) { return __uint_as_float(u << 16); }
__device__ __forceinline__ float bfhi(unsigned u) { return __uint_as_float(u & 0xffff0000u); }

// ---------------------------------------------------------------------------
// Fused prep (same as R10):
//   blocks [0,5000):    XCD-partitioned fill (chunk = b>>3, region = b&7)
//   blocks [5000,7500): convert x -> bf16
//   blocks [7500,7532): pack W1/W2 into MFMA B-fragment layout
// ---------------------------------------------------------------------------
__global__ __launch_bounds__(256) void prep_kernel(
    const float* __restrict__ x,
    const int* __restrict__ src, const int* __restrict__ dst,
    const float* __restrict__ W1_rel, const float* __restrict__ W1_root,
    const float* __restrict__ W2_rel, const float* __restrict__ W2_root,
    int* __restrict__ cnt, unsigned short* __restrict__ buckets,
    short* __restrict__ xb, short* __restrict__ wpk1, short* __restrict__ wpk2)
{
    const int b = blockIdx.x;
    const int tid = threadIdx.x;
    if (b < 5000) {
        const int chunk  = b >> 3;
        const int region = b & (NREG - 1);
        int e4 = chunk * 256 + tid;
        int4 s4 = ((const int4*)src)[e4];
        int4 d4 = ((const int4*)dst)[e4];
#pragma unroll
        for (int q = 0; q < 4; q++) {
            int d = (&d4.x)[q];
            int s = (&s4.x)[q];
            if (d / REGSZ == region) {
                int p = atomicAdd(&cnt[d], 1);
                if (p < CAP) buckets[(d << 7) + p] = (unsigned short)s;
            }
        }
    } else if (b < 7500) {
        int i = (b - 5000) * 256 + tid;
        float4 v = ((const float4*)x)[i];
        ushort4 o;
        o.x = (unsigned short)f2bf(v.x);
        o.y = (unsigned short)f2bf(v.y);
        o.z = (unsigned short)f2bf(v.z);
        o.w = (unsigned short)f2bf(v.w);
        ((ushort4*)xb)[i] = o;
    } else {
        int pb  = b - 7500;
        int job = pb >> 4;
        int idx = (pb & 15) * 256 + tid;
        const float* Wrel  = job ? W2_rel  : W1_rel;
        const float* Wroot = job ? W2_root : W1_root;
        short* Wpk = job ? wpk2 : wpk1;
        int lane = idx & 63;
        int ct   = (idx >> 6) & 7;
        int t    = idx >> 9;
        const float* W = (t < 4) ? Wrel : Wroot;
        int k0  = (t & 3) * 32 + (lane >> 4) * 8;
        int col = ct * 16 + (lane & 15);
        bf16x8 pk;
#pragma unroll
        for (int j = 0; j < 8; j++)
            pk[j] = f2bf(W[(size_t)(k0 + j) * D + col]);
        ((bf16x8*)Wpk)[idx] = pk;
    }
}

// ---------------------------------------------------------------------------
// Fused layer: out = [relu]( agg @ Wrel + b + x @ Wroot ), virtual K=256 GEMM.
// 512 threads, 16 nodes/block.
// Phase 1 (gather, k-split): two passes over D/2=64 cols each; per pass the
//   gather table slice is 2.56MB -> L2-resident per XCD (latency ~200cyc vs
//   600-900 miss). Bucket indices held in registers across both passes; shfl
//   broadcast; 16 x 4B-lane loads in flight.
// Phase 2 (MFMA): wave = 16-col tile, K=256 (LDS agg + global x + packed W).
// ---------------------------------------------------------------------------
template <bool RELU, bool OUT_BF16>
__global__ __launch_bounds__(512) void layer_kernel(
    const short* __restrict__ xin,
    const int* __restrict__ cnt,
    const unsigned short* __restrict__ buckets,
    const short* __restrict__ Wpk,
    const float* __restrict__ brel,
    void* __restrict__ outp)
{
    __shared__ short sAgg[16][136];

    const int tid  = threadIdx.x;
    const int row0 = blockIdx.x * 16;

    // ---- phase 1: k-split gather-aggregate into LDS ----
    {
        const int hw   = tid >> 5;       // 0..15 -> node
        const int lane = tid & 31;
        const int node = row0 + hw;
        int n = cnt[node];
        n = (n > CAP) ? CAP : n;
        uint2 idxpk = *(const uint2*)(buckets + (node << 7) + lane * 4);

#pragma unroll
        for (int h = 0; h < 2; h++) {
            const short* xbase = xin + h * 64 + lane * 2;  // this lane's 2 cols
            float acx = 0.f, acy = 0.f;
            int i = 0;
            for (; i + 16 <= n; i += 16) {
                unsigned u[16];
#pragma unroll
                for (int q = 0; q < 16; q++) {
                    int j = i + q;
                    unsigned word = __shfl((j & 2) ? idxpk.y : idxpk.x, j >> 2, 32);
                    unsigned sidx = (j & 1) ? (word >> 16) : (word & 0xffffu);
                    u[q] = *(const unsigned*)(xbase + (size_t)sidx * D);
                }
#pragma unroll
                for (int q = 0; q < 16; q++) { acx += bflo(u[q]); acy += bfhi(u[q]); }
            }
            for (; i + 4 <= n; i += 4) {
                unsigned u[4];
#pragma unroll
                for (int q = 0; q < 4; q++) {
                    int j = i + q;
                    unsigned word = __shfl((j & 2) ? idxpk.y : idxpk.x, j >> 2, 32);
                    unsigned sidx = (j & 1) ? (word >> 16) : (word & 0xffffu);
                    u[q] = *(const unsigned*)(xbase + (size_t)sidx * D);
                }
#pragma unroll
                for (int q = 0; q < 4; q++) { acx += bflo(u[q]); acy += bfhi(u[q]); }
            }
            for (; i < n; i++) {
                unsigned word = __shfl((i & 2) ? idxpk.y : idxpk.x, i >> 2, 32);
                unsigned sidx = (i & 1) ? (word >> 16) : (word & 0xffffu);
                unsigned u0 = *(const unsigned*)(xbase + (size_t)sidx * D);
                acx += bflo(u0); acy += bfhi(u0);
            }
            unsigned pk = ((unsigned)(unsigned short)f2bf(acx))
                        | (((unsigned)(unsigned short)f2bf(acy)) << 16);
            *(unsigned*)&sAgg[hw][h * 64 + lane * 2] = pk;
        }
    }
    __syncthreads();

    // ---- phase 2: MFMA, wave = one 16-col tile ----
    const int wave = tid >> 6;
    const int lane = tid & 63;
    const int quad = lane >> 4;
    const int l16  = lane & 15;

    f32x4 acc = (f32x4){0.f, 0.f, 0.f, 0.f};
    const short* arow_x = xin + (size_t)(row0 + l16) * D + quad * 8;
    const bf16x8* wb = (const bf16x8*)Wpk + lane;

#pragma unroll
    for (int t = 0; t < 8; t++) {
        bf16x8 a;
        if (t < 4)
            a = *(const bf16x8*)&sAgg[l16][(t & 3) * 32 + quad * 8];
        else
            a = *(const bf16x8*)(arow_x + (t & 3) * 32);
        bf16x8 bfr = wb[(t * 8 + wave) * 64];
        acc = __builtin_amdgcn_mfma_f32_16x16x32_bf16(a, bfr, acc, 0, 0, 0);
    }

    const int col  = wave * 16 + l16;
    const int orow = row0 + quad * 4;
    const float bias = brel[col];
#pragma unroll
    for (int r = 0; r < 4; r++) {
        float v = acc[r] + bias;
        if (RELU) v = fmaxf(v, 0.f);
        if (OUT_BF16)
            ((short*)outp)[(size_t)(orow + r) * D + col] = f2bf(v);
        else
            ((float*)outp)[(size_t)(orow + r) * D + col] = v;
    }
}

// ---------------------------------------------------------------------------
extern "C" void kernel_launch(void* const* d_in, const int* in_sizes, int n_in,
                              void* d_out, int out_size, void* d_ws, size_t ws_size,
                              hipStream_t stream) {
    const float* x       = (const float*)d_in[0];
    const int*   ei      = (const int*)  d_in[1];
    const float* W1_rel  = (const float*)d_in[2];
    const float* b1_rel  = (const float*)d_in[3];
    const float* W1_root = (const float*)d_in[4];
    const float* W2_rel  = (const float*)d_in[5];
    const float* b2_rel  = (const float*)d_in[6];
    const float* W2_root = (const float*)d_in[7];
    float* out = (float*)d_out;

    // ws layout (16B-aligned blocks)
    char* p = (char*)d_ws;
    short* xb   = (short*)p;  p += (size_t)N_NODES * D * 2;   // 5.12 MB
    short* hb   = (short*)p;  p += (size_t)N_NODES * D * 2;   // 5.12 MB
    short* wpk1 = (short*)p;  p += 65536;                     // 64 KB
    short* wpk2 = (short*)p;  p += 65536;                     // 64 KB
    int*   cnt  = (int*)p;    p += (size_t)N_NODES * 4;       // 80 KB
    unsigned short* buckets = (unsigned short*)p;             // 5.12 MB

    const int* src = ei;
    const int* dst = ei + N_EDGES;

    const int layerblocks = N_NODES / 16;   // 1250

    // ---- prep: zero counters, then fused partitioned-fill+convert+pack ----
    hipMemsetAsync(cnt, 0, (size_t)N_NODES * sizeof(int), stream);
    prep_kernel<<<7532, 256, 0, stream>>>(
        x, src, dst, W1_rel, W1_root, W2_rel, W2_root,
        cnt, buckets, xb, wpk1, wpk2);

    // ---- layer 1 (x -> hb, bf16, relu) ----
    layer_kernel<true, true><<<layerblocks, 512, 0, stream>>>(
        xb, cnt, buckets, wpk1, b1_rel, (void*)hb);

    // ---- layer 2 (hb -> out, fp32) ----
    layer_kernel<false, false><<<layerblocks, 512, 0, stream>>>(
        hb, cnt, buckets, wpk2, b2_rel, (void*)out);
}